// Round 6
// baseline (154.055 us; speedup 1.0000x reference)
//
#include <hip/hip_runtime.h>
#include <math.h>

#define S 128
#define H 64
#define RPB 4            // rays per block (one per wave)
#define SPB (RPB * S)    // 512 samples per block
#define T 256

// ---------------------------------------------------------------------------
// Exact-geometry occupancy mask (identical op sequence since round 0;
// _rn intrinsics forbid fma contraction so floor() cells bit-match numpy).
// ---------------------------------------------------------------------------
__device__ __forceinline__ bool sample_mask(
    float ox, float oy, float oz, float dx, float dy, float dz,
    float nr, float step, int s, const float* __restrict__ density)
{
    const float z  = __fadd_rn(nr, __fmul_rn((float)s, step));
    const float px = __fadd_rn(ox, __fmul_rn(z, dx));
    const float py = __fadd_rn(oy, __fmul_rn(z, dy));
    const float pz = __fadd_rn(oz, __fmul_rn(z, dz));
    const float gx = floorf(__fmul_rn(__fdiv_rn(__fsub_rn(px, -1.25f), 2.5f), 64.0f));
    const float gy = floorf(__fmul_rn(__fdiv_rn(__fsub_rn(py, -1.55f), 2.5f), 64.0f));
    const float gz = floorf(__fmul_rn(__fdiv_rn(__fsub_rn(pz, -1.25f), 2.5f), 64.0f));
    const int ix = (int)gx, iy = (int)gy, iz = (int)gz;
    const bool inb = (ix >= 0) && (ix < 64) && (iy >= 0) && (iy < 64) &&
                     (iz >= 0) && (iz < 64);
    const int cx = min(max(ix, 0), 63);
    const int cy = min(max(iy, 0), 63);
    const int cz = min(max(iz, 0), 63);
    const float dval = density[(cx << 12) | (cy << 6) | cz];
    return inb && (dval > 0.5f);
}

// ---------------------------------------------------------------------------
// Fused per-block kernel: 4 rays / block, 256 threads (4 waves, one ray per
// wave in phases A and C). Everything stays in LDS — no workspace, no global
// atomics, no memset node, no multi-kernel dispatch tails:
//   Phase A: mask 2 samples/thread (ray data wave-uniform -> scalarized),
//            wave shuffle-scan + 4-entry LDS scan -> block-compacted s_list.
//   Phase B: MLP over the K ~ 230 active samples with 256 threads (~90% lane
//            utilization); weights read wave-uniform from global -> s_load
//            through the scalar cache (verified: VGPR 48, vector pipe = FMAs).
//   Phase C: per-wave shuffle product-scan composite, 3 floats out per ray.
// ---------------------------------------------------------------------------
__global__ __launch_bounds__(256)
void fused_block_kernel(const float* __restrict__ rays_o, const float* __restrict__ rays_d,
                        const float* __restrict__ nearv, const float* __restrict__ farv,
                        const float* __restrict__ jitter, const float* __restrict__ density,
                        const float* __restrict__ W1, const float* __restrict__ b1,
                        const float* __restrict__ W2, const float* __restrict__ b2,
                        const float* __restrict__ Wsig, const float* __restrict__ bsig,
                        const float* __restrict__ Wrgb, const float* __restrict__ brgb,
                        float* __restrict__ out, int N)
{
    __shared__ unsigned short s_list[SPB];   // 1 KB
    __shared__ float s_alpha[SPB];           // 2 KB
    __shared__ float s_r[SPB], s_g[SPB], s_b[SPB];  // 6 KB
    __shared__ int s_wcnt[4];
    __shared__ int s_wbase[4];

    const int tid  = threadIdx.x;
    const int lane = tid & 63;
    const int wv   = tid >> 6;
    const int blk  = blockIdx.x;

    // ================= Phase A: mask + block compaction =================
    const int gr    = blk * RPB + wv;   // this wave's ray
    const int lbase = tid * 2;          // local sample ids lbase, lbase+1
    unsigned int mybits = 0u;
    if (gr < N) {
        const float ox = rays_o[gr * 3 + 0], oy = rays_o[gr * 3 + 1], oz = rays_o[gr * 3 + 2];
        const float dx = rays_d[gr * 3 + 0], dy = rays_d[gr * 3 + 1], dz = rays_d[gr * 3 + 2];
        const float nr = nearv[gr];
        const float step = __fdiv_rn(__fsub_rn(farv[gr], nr), 128.0f);
        const int s0 = lane * 2;
        #pragma unroll
        for (int j = 0; j < 2; ++j) {
            const bool m = sample_mask(ox, oy, oz, dx, dy, dz, nr, step, s0 + j, density);
            if (m) mybits |= (1u << j);
            else   s_alpha[lbase + j] = 0.0f;   // active samples written in phase B
        }
    } else {
        s_alpha[lbase] = 0.0f;
        s_alpha[lbase + 1] = 0.0f;
    }
    const int mycnt = __popc(mybits);
    int inc = mycnt;
    #pragma unroll
    for (int off = 1; off < 64; off <<= 1) {
        const int u = __shfl_up(inc, off, 64);
        if (lane >= off) inc += u;
    }
    if (lane == 63) s_wcnt[wv] = inc;
    __syncthreads();
    if (tid == 0) {
        int t = 0;
        #pragma unroll
        for (int i = 0; i < 4; ++i) { s_wbase[i] = t; t += s_wcnt[i]; }
    }
    __syncthreads();
    int pos = s_wbase[wv] + (inc - mycnt);
    if (mybits & 1u) s_list[pos++] = (unsigned short)lbase;
    if (mybits & 2u) s_list[pos]   = (unsigned short)(lbase + 1);
    __syncthreads();
    const int K = s_wbase[3] + s_wcnt[3];

    // ================= Phase B: MLP over compacted samples =================
    for (int i = tid; i < K; i += T) {
        const int id = s_list[i];
        const int r  = blk * RPB + (id >> 7);
        const int s  = id & (S - 1);
        const float nr = nearv[r];
        const float step = __fdiv_rn(__fsub_rn(farv[r], nr), 128.0f);
        const float zs = __fadd_rn(nr, __fmul_rn((float)s, step));
        const float zj = zs + jitter[blk * SPB + id] * step;
        const float qx = rays_o[r * 3 + 0] + zj * rays_d[r * 3 + 0];
        const float qy = rays_o[r * 3 + 1] + zj * rays_d[r * 3 + 1];
        const float qz = rays_o[r * 3 + 2] + zj * rays_d[r * 3 + 2];

        float h2[H];
        #pragma unroll
        for (int j = 0; j < H; ++j) h2[j] = b2[j];

        for (int k = 0; k < H; ++k) {
            const float h1k = fmaxf(
                fmaf(qx, W1[k], fmaf(qy, W1[H + k], fmaf(qz, W1[2 * H + k], b1[k]))), 0.0f);
            const float4* __restrict__ w2v = reinterpret_cast<const float4*>(W2 + (k << 6));
            #pragma unroll
            for (int j4 = 0; j4 < H / 4; ++j4) {
                const float4 w = w2v[j4];
                h2[4 * j4 + 0] = fmaf(h1k, w.x, h2[4 * j4 + 0]);
                h2[4 * j4 + 1] = fmaf(h1k, w.y, h2[4 * j4 + 1]);
                h2[4 * j4 + 2] = fmaf(h1k, w.z, h2[4 * j4 + 2]);
                h2[4 * j4 + 3] = fmaf(h1k, w.w, h2[4 * j4 + 3]);
            }
        }

        float sig = bsig[0], cr = brgb[0], cg = brgb[1], cb = brgb[2];
        #pragma unroll
        for (int j = 0; j < H; ++j) {
            const float v = fmaxf(h2[j], 0.0f);
            sig = fmaf(v, Wsig[j], sig);
            cr  = fmaf(v, Wrgb[j * 3 + 0], cr);
            cg  = fmaf(v, Wrgb[j * 3 + 1], cg);
            cb  = fmaf(v, Wrgb[j * 3 + 2], cb);
        }
        const float tau = fmaxf(sig, 0.0f) * step;
        s_alpha[id] = 1.0f - expf(-tau);
        s_r[id] = 1.0f / (1.0f + expf(-cr));
        s_g[id] = 1.0f / (1.0f + expf(-cg));
        s_b[id] = 1.0f / (1.0f + expf(-cb));
    }
    __syncthreads();

    // ================= Phase C: composite (ray wv per wave) =================
    if (gr < N) {
        const int b0 = wv * S + 2 * lane;
        const float2 a01 = *reinterpret_cast<const float2*>(&s_alpha[b0]);
        const float a0 = a01.x, a1 = a01.y;
        const float t0 = (1.0f - a0) + 1e-10f;
        const float t1 = (1.0f - a1) + 1e-10f;
        float v = t0 * t1;
        #pragma unroll
        for (int off = 1; off < 64; off <<= 1) {
            const float u = __shfl_up(v, off, 64);
            if (lane >= off) v *= u;
        }
        float excl = __shfl_up(v, 1, 64);
        if (lane == 0) excl = 1.0f;
        const float no_hit = __shfl(v, 63, 64);
        const float w0 = a0 * excl;
        const float w1 = a1 * (excl * t0);
        const float2 r01 = *reinterpret_cast<const float2*>(&s_r[b0]);
        const float2 g01 = *reinterpret_cast<const float2*>(&s_g[b0]);
        const float2 b01 = *reinterpret_cast<const float2*>(&s_b[b0]);
        float cr = w0 * r01.x + w1 * r01.y;
        float cg = w0 * g01.x + w1 * g01.y;
        float cb = w0 * b01.x + w1 * b01.y;
        #pragma unroll
        for (int off = 32; off >= 1; off >>= 1) {
            cr += __shfl_xor(cr, off, 64);
            cg += __shfl_xor(cg, off, 64);
            cb += __shfl_xor(cb, off, 64);
        }
        if (lane == 0) {
            out[gr * 3 + 0] = cr + no_hit;
            out[gr * 3 + 1] = cg + no_hit;
            out[gr * 3 + 2] = cb + no_hit;
        }
    }
}

extern "C" void kernel_launch(void* const* d_in, const int* in_sizes, int n_in,
                              void* d_out, int out_size, void* d_ws, size_t ws_size,
                              hipStream_t stream) {
    const float* rays_o  = (const float*)d_in[0];
    const float* rays_d  = (const float*)d_in[1];
    const float* nearv   = (const float*)d_in[2];
    const float* farv    = (const float*)d_in[3];
    const float* jitter  = (const float*)d_in[4];
    const float* density = (const float*)d_in[5];
    const float* W1      = (const float*)d_in[6];
    const float* b1      = (const float*)d_in[7];
    const float* W2      = (const float*)d_in[8];
    const float* b2      = (const float*)d_in[9];
    const float* Wsig    = (const float*)d_in[10];
    const float* bsig    = (const float*)d_in[11];
    const float* Wrgb    = (const float*)d_in[12];
    const float* brgb    = (const float*)d_in[13];
    float* out = (float*)d_out;

    const int N = in_sizes[2];

    fused_block_kernel<<<dim3((N + RPB - 1) / RPB), dim3(T), 0, stream>>>(
        rays_o, rays_d, nearv, farv, jitter, density,
        W1, b1, W2, b2, Wsig, bsig, Wrgb, brgb, out, N);
}

// Round 8
// 109.474 us; speedup vs baseline: 1.4072x; 1.4072x over previous
//
#include <hip/hip_runtime.h>
#include <math.h>

#define S 128
#define H 64
#define RPB 4            // rays per block (one per wave in phases A/C)
#define SPB (RPB * S)    // 512 samples per block
#define T 256

typedef __attribute__((ext_vector_type(8))) short bf16x8;
typedef __attribute__((ext_vector_type(4))) float f32x4;
#define MFMA16(a, b, c) __builtin_amdgcn_mfma_f32_16x16x32_bf16((a), (b), (c), 0, 0, 0)

// RNE float->bf16 (bit pattern as short)
__device__ __forceinline__ short f2bf(float x) {
    unsigned u = __float_as_uint(x);
    unsigned r = (u + 0x7fffu + ((u >> 16) & 1u)) >> 16;
    return (short)r;
}

// ---------------------------------------------------------------------------
// Exact-geometry occupancy mask (identical op sequence since round 0;
// _rn intrinsics forbid fma contraction so floor() cells bit-match numpy).
// ---------------------------------------------------------------------------
__device__ __forceinline__ bool sample_mask(
    float ox, float oy, float oz, float dx, float dy, float dz,
    float nr, float step, int s, const float* __restrict__ density)
{
    const float z  = __fadd_rn(nr, __fmul_rn((float)s, step));
    const float px = __fadd_rn(ox, __fmul_rn(z, dx));
    const float py = __fadd_rn(oy, __fmul_rn(z, dy));
    const float pz = __fadd_rn(oz, __fmul_rn(z, dz));
    const float gx = floorf(__fmul_rn(__fdiv_rn(__fsub_rn(px, -1.25f), 2.5f), 64.0f));
    const float gy = floorf(__fmul_rn(__fdiv_rn(__fsub_rn(py, -1.55f), 2.5f), 64.0f));
    const float gz = floorf(__fmul_rn(__fdiv_rn(__fsub_rn(pz, -1.25f), 2.5f), 64.0f));
    const int ix = (int)gx, iy = (int)gy, iz = (int)gz;
    const bool inb = (ix >= 0) && (ix < 64) && (iy >= 0) && (iy < 64) &&
                     (iz >= 0) && (iz < 64);
    const int cx = min(max(ix, 0), 63);
    const int cy = min(max(iy, 0), 63);
    const int cz = min(max(iz, 0), 63);
    const float dval = density[(cx << 12) | (cy << 6) | cz];
    return inb && (dval > 0.5f);
}

// ---------------------------------------------------------------------------
// Fused kernel: phase A mask+compact (verified), phase B MFMA MLP over
// 16-sample wave-tasks, phase C wave composite (verified).
//
// MFMA layouts (16x16x32 bf16, HW-verified m89/m91/m120):
//   A-frag: lane holds A[m=lane&15][k=8*quad+j], j=0..7   (quad=lane>>4)
//   B-frag: lane holds B[k=8*quad+j][n=lane&15]
//   C/D:    reg r = C[row=4*quad+r][col=lane&15]
// L3 is computed swapped (D = W3^T * relu(h2)) so C cols = samples and
// C rows = channels: quad-0 lanes hold all 4 channels of their sample ->
// shuffle-free epilogue.
//
// BUGFIX vs round 7: s_r/s_g/s_b are now zeroed for inactive samples in
// phase A. They were uninitialized LDS; phase C computed 0*garbage which
// is NaN when the stale bits alias a NaN pattern (round 6 passed on luck).
// ---------------------------------------------------------------------------
__global__ __launch_bounds__(256)
void fused_mfma_kernel(const float* __restrict__ rays_o, const float* __restrict__ rays_d,
                       const float* __restrict__ nearv, const float* __restrict__ farv,
                       const float* __restrict__ jitter, const float* __restrict__ density,
                       const float* __restrict__ W1, const float* __restrict__ b1,
                       const float* __restrict__ W2, const float* __restrict__ b2,
                       const float* __restrict__ Wsig, const float* __restrict__ bsig,
                       const float* __restrict__ Wrgb, const float* __restrict__ brgb,
                       float* __restrict__ out, int N)
{
    __shared__ __align__(16) short sW2[H * 68];        // staged bf16 W2 [k][n], 8.7 KB
    __shared__ __align__(16) short h1h[4][16 * 72];    // per-wave h1 bf16 [row][col], 9.2 KB
    __shared__ __align__(16) short h2b[4][16 * 72];    // per-wave relu(h2) bf16, 9.2 KB
    __shared__ unsigned short s_list[SPB];             // 1 KB
    __shared__ float s_alpha[SPB];                     // 2 KB
    __shared__ float s_r[SPB], s_g[SPB], s_b[SPB];     // 6 KB
    __shared__ int s_wcnt[4];
    __shared__ int s_wbase[4];

    const int tid  = threadIdx.x;
    const int lane = tid & 63;
    const int wv   = tid >> 6;
    const int blk  = blockIdx.x;
    const int mrow = lane & 15;      // 16-dim index (row for A/C, col for B)
    const int quad = lane >> 4;      // k-quad

    // ---- stage W2 as bf16 into LDS (coalesced) ----
    for (int e = tid; e < H * H; e += T) {
        const int k = e >> 6, n = e & 63;
        sW2[k * 68 + n] = f2bf(W2[e]);
    }

    // ================= Phase A: mask + block compaction =================
    const int gr    = blk * RPB + wv;   // this wave's ray
    const int lbase = tid * 2;
    unsigned int mybits = 0u;
    if (gr < N) {
        const float ox = rays_o[gr * 3 + 0], oy = rays_o[gr * 3 + 1], oz = rays_o[gr * 3 + 2];
        const float dx = rays_d[gr * 3 + 0], dy = rays_d[gr * 3 + 1], dz = rays_d[gr * 3 + 2];
        const float nr = nearv[gr];
        const float step = __fdiv_rn(__fsub_rn(farv[gr], nr), 128.0f);
        const int s0 = lane * 2;
        #pragma unroll
        for (int j = 0; j < 2; ++j) {
            const bool m = sample_mask(ox, oy, oz, dx, dy, dz, nr, step, s0 + j, density);
            if (m) {
                mybits |= (1u << j);
            } else {
                s_alpha[lbase + j] = 0.0f;
                s_r[lbase + j] = 0.0f;
                s_g[lbase + j] = 0.0f;
                s_b[lbase + j] = 0.0f;
            }
        }
    } else {
        #pragma unroll
        for (int j = 0; j < 2; ++j) {
            s_alpha[lbase + j] = 0.0f;
            s_r[lbase + j] = 0.0f;
            s_g[lbase + j] = 0.0f;
            s_b[lbase + j] = 0.0f;
        }
    }
    const int mycnt = __popc(mybits);
    int inc = mycnt;
    #pragma unroll
    for (int off = 1; off < 64; off <<= 1) {
        const int u = __shfl_up(inc, off, 64);
        if (lane >= off) inc += u;
    }
    if (lane == 63) s_wcnt[wv] = inc;
    __syncthreads();                       // also covers sW2 staging
    if (tid == 0) {
        int t0 = 0;
        #pragma unroll
        for (int i = 0; i < 4; ++i) { s_wbase[i] = t0; t0 += s_wcnt[i]; }
    }
    __syncthreads();
    int pos = s_wbase[wv] + (inc - mycnt);
    if (mybits & 1u) s_list[pos++] = (unsigned short)lbase;
    if (mybits & 2u) s_list[pos]   = (unsigned short)(lbase + 1);
    __syncthreads();
    const int K = s_wbase[3] + s_wcnt[3];

    // ================= Phase B: weight fragments (once per block) ===========
    bf16x8 w2f[4][2];
    #pragma unroll
    for (int nt = 0; nt < 4; ++nt) {
        #pragma unroll
        for (int ks = 0; ks < 2; ++ks) {
            bf16x8 f;
            #pragma unroll
            for (int j = 0; j < 8; ++j)
                f[j] = sW2[(32 * ks + 8 * quad + j) * 68 + mrow + 16 * nt];
            w2f[nt][ks] = f;
        }
    }
    // W1 B-frags: rows k=0..2 = input dims (bias added fp32 in epilogue)
    bf16x8 w1f[4];
    #pragma unroll
    for (int nt = 0; nt < 4; ++nt) {
        bf16x8 f = {0, 0, 0, 0, 0, 0, 0, 0};
        if (quad == 0) {
            const int n = mrow + 16 * nt;
            f[0] = f2bf(W1[n]);
            f[1] = f2bf(W1[64 + n]);
            f[2] = f2bf(W1[128 + n]);
        }
        w1f[nt] = f;
    }
    // L3 A-frags: A[m=channel][k]; ch0=Wsig, ch1..3=Wrgb
    bf16x8 a3f[2];
    #pragma unroll
    for (int ks = 0; ks < 2; ++ks) {
        bf16x8 f = {0, 0, 0, 0, 0, 0, 0, 0};
        if (mrow < 4) {
            #pragma unroll
            for (int j = 0; j < 8; ++j) {
                const int k = 32 * ks + 8 * quad + j;
                const float v = (mrow == 0) ? Wsig[k] : Wrgb[k * 3 + (mrow - 1)];
                f[j] = f2bf(v);
            }
        }
        a3f[ks] = f;
    }
    float b1v[4], b2v[4];
    #pragma unroll
    for (int nt = 0; nt < 4; ++nt) {
        b1v[nt] = b1[mrow + 16 * nt];
        b2v[nt] = b2[mrow + 16 * nt];
    }
    const float bsg = bsig[0];
    const float br0 = brgb[0], br1 = brgb[1], br2 = brgb[2];

    // ================= Phase B: MFMA MLP over 16-sample tasks ===============
    const f32x4 z4 = {0.f, 0.f, 0.f, 0.f};
    const int ntask = (K + 15) >> 4;
    short* const hb = &h1h[wv][0];
    short* const gb = &h2b[wv][0];

    for (int t = wv; t < ntask; t += 4) {
        const int slot = (t << 4) + mrow;
        const bool valid = slot < K;
        const int id = s_list[valid ? slot : 0];
        const int r = blk * RPB + (id >> 7);
        const int s = id & (S - 1);
        const float nr = nearv[r];
        const float step = __fdiv_rn(__fsub_rn(farv[r], nr), 128.0f);
        const float zs = __fadd_rn(nr, __fmul_rn((float)s, step));
        const float zj = zs + jitter[blk * SPB + id] * step;
        const float qx = rays_o[r * 3 + 0] + zj * rays_d[r * 3 + 0];
        const float qy = rays_o[r * 3 + 1] + zj * rays_d[r * 3 + 1];
        const float qz = rays_o[r * 3 + 2] + zj * rays_d[r * 3 + 2];

        // ---- L1: A = pts (k=0..2 on quad 0) ----
        bf16x8 ah = {0, 0, 0, 0, 0, 0, 0, 0};
        if (quad == 0) { ah[0] = f2bf(qx); ah[1] = f2bf(qy); ah[2] = f2bf(qz); }
        #pragma unroll
        for (int nt = 0; nt < 4; ++nt) {
            const f32x4 c1 = MFMA16(ah, w1f[nt], z4);
            #pragma unroll
            for (int rg = 0; rg < 4; ++rg) {
                const float v = fmaxf(c1[rg] + b1v[nt], 0.0f);
                hb[(4 * quad + rg) * 72 + mrow + 16 * nt] = f2bf(v);
            }
        }

        // ---- L2: h2 = relu(h1) @ W2 ----
        bf16x8 a2_0 = *(const bf16x8*)&hb[mrow * 72 + 8 * quad];
        bf16x8 a2_1 = *(const bf16x8*)&hb[mrow * 72 + 32 + 8 * quad];
        #pragma unroll
        for (int nt = 0; nt < 4; ++nt) {
            const f32x4 c2 = MFMA16(a2_1, w2f[nt][1], MFMA16(a2_0, w2f[nt][0], z4));
            #pragma unroll
            for (int rg = 0; rg < 4; ++rg) {
                const float v = fmaxf(c2[rg] + b2v[nt], 0.0f);
                gb[(4 * quad + rg) * 72 + mrow + 16 * nt] = f2bf(v);
            }
        }

        // ---- L3 (swapped): D = W3^T @ relu(h2); C cols=samples, rows=channels
        bf16x8 b3_0 = *(const bf16x8*)&gb[mrow * 72 + 8 * quad];
        bf16x8 b3_1 = *(const bf16x8*)&gb[mrow * 72 + 32 + 8 * quad];
        const f32x4 c3 = MFMA16(a3f[1], b3_1, MFMA16(a3f[0], b3_0, z4));

        if (quad == 0 && valid) {
            const float sg = c3[0] + bsg;
            const float tau = fmaxf(sg, 0.0f) * step;
            s_alpha[id] = 1.0f - expf(-tau);
            s_r[id] = 1.0f / (1.0f + expf(-(c3[1] + br0)));
            s_g[id] = 1.0f / (1.0f + expf(-(c3[2] + br1)));
            s_b[id] = 1.0f / (1.0f + expf(-(c3[3] + br2)));
        }
    }
    __syncthreads();

    // ================= Phase C: composite (verified) ========================
    if (gr < N) {
        const int b0 = wv * S + 2 * lane;
        const float2 a01 = *reinterpret_cast<const float2*>(&s_alpha[b0]);
        const float a0 = a01.x, a1 = a01.y;
        const float t0 = (1.0f - a0) + 1e-10f;
        const float t1 = (1.0f - a1) + 1e-10f;
        float v = t0 * t1;
        #pragma unroll
        for (int off = 1; off < 64; off <<= 1) {
            const float u = __shfl_up(v, off, 64);
            if (lane >= off) v *= u;
        }
        float excl = __shfl_up(v, 1, 64);
        if (lane == 0) excl = 1.0f;
        const float no_hit = __shfl(v, 63, 64);
        const float w0 = a0 * excl;
        const float w1 = a1 * (excl * t0);
        const float2 r01 = *reinterpret_cast<const float2*>(&s_r[b0]);
        const float2 g01 = *reinterpret_cast<const float2*>(&s_g[b0]);
        const float2 b01 = *reinterpret_cast<const float2*>(&s_b[b0]);
        float cr = w0 * r01.x + w1 * r01.y;
        float cg = w0 * g01.x + w1 * g01.y;
        float cb = w0 * b01.x + w1 * b01.y;
        #pragma unroll
        for (int off = 32; off >= 1; off >>= 1) {
            cr += __shfl_xor(cr, off, 64);
            cg += __shfl_xor(cg, off, 64);
            cb += __shfl_xor(cb, off, 64);
        }
        if (lane == 0) {
            out[gr * 3 + 0] = cr + no_hit;
            out[gr * 3 + 1] = cg + no_hit;
            out[gr * 3 + 2] = cb + no_hit;
        }
    }
}

extern "C" void kernel_launch(void* const* d_in, const int* in_sizes, int n_in,
                              void* d_out, int out_size, void* d_ws, size_t ws_size,
                              hipStream_t stream) {
    const float* rays_o  = (const float*)d_in[0];
    const float* rays_d  = (const float*)d_in[1];
    const float* nearv   = (const float*)d_in[2];
    const float* farv    = (const float*)d_in[3];
    const float* jitter  = (const float*)d_in[4];
    const float* density = (const float*)d_in[5];
    const float* W1      = (const float*)d_in[6];
    const float* b1      = (const float*)d_in[7];
    const float* W2      = (const float*)d_in[8];
    const float* b2      = (const float*)d_in[9];
    const float* Wsig    = (const float*)d_in[10];
    const float* bsig    = (const float*)d_in[11];
    const float* Wrgb    = (const float*)d_in[12];
    const float* brgb    = (const float*)d_in[13];
    float* out = (float*)d_out;

    const int N = in_sizes[2];

    fused_mfma_kernel<<<dim3((N + RPB - 1) / RPB), dim3(T), 0, stream>>>(
        rays_o, rays_d, nearv, farv, jitter, density,
        W1, b1, W2, b2, Wsig, bsig, Wrgb, brgb, out, N);
}

// Round 9
// 105.206 us; speedup vs baseline: 1.4643x; 1.0406x over previous
//
#include <hip/hip_runtime.h>
#include <math.h>

#define S 128
#define H 64
#define RPB 8            // rays per block
#define SPB (RPB * S)    // 1024 samples per block
#define T 256

typedef __attribute__((ext_vector_type(8))) short bf16x8;
typedef __attribute__((ext_vector_type(4))) float f32x4;
#define MFMA16(a, b, c) __builtin_amdgcn_mfma_f32_16x16x32_bf16((a), (b), (c), 0, 0, 0)

// RNE float->bf16 (bit pattern as short)
__device__ __forceinline__ short f2bf(float x) {
    unsigned u = __float_as_uint(x);
    unsigned r = (u + 0x7fffu + ((u >> 16) & 1u)) >> 16;
    return (short)r;
}

// ---------------------------------------------------------------------------
// Exact-geometry occupancy mask (identical op sequence since round 0;
// _rn intrinsics forbid fma contraction so floor() cells bit-match numpy).
// ---------------------------------------------------------------------------
__device__ __forceinline__ bool sample_mask(
    float ox, float oy, float oz, float dx, float dy, float dz,
    float nr, float step, int s, const float* __restrict__ density)
{
    const float z  = __fadd_rn(nr, __fmul_rn((float)s, step));
    const float px = __fadd_rn(ox, __fmul_rn(z, dx));
    const float py = __fadd_rn(oy, __fmul_rn(z, dy));
    const float pz = __fadd_rn(oz, __fmul_rn(z, dz));
    const float gx = floorf(__fmul_rn(__fdiv_rn(__fsub_rn(px, -1.25f), 2.5f), 64.0f));
    const float gy = floorf(__fmul_rn(__fdiv_rn(__fsub_rn(py, -1.55f), 2.5f), 64.0f));
    const float gz = floorf(__fmul_rn(__fdiv_rn(__fsub_rn(pz, -1.25f), 2.5f), 64.0f));
    const int ix = (int)gx, iy = (int)gy, iz = (int)gz;
    const bool inb = (ix >= 0) && (ix < 64) && (iy >= 0) && (iy < 64) &&
                     (iz >= 0) && (iz < 64);
    const int cx = min(max(ix, 0), 63);
    const int cy = min(max(iy, 0), 63);
    const int cz = min(max(iz, 0), 63);
    const float dval = density[(cx << 12) | (cy << 6) | cz];
    return inb && (dval > 0.5f);
}

// ---------------------------------------------------------------------------
// Fused kernel, round 9:
//  - RPB=8: per-block setup (W2 staging, fragment builds) amortized over 2x
//    samples; 1024 blocks.
//  - W2 staged TRANSPOSED [n][k] so each B-frag load is one ds_read_b128
//    (round-8 gathered 64 ds_read_u16 per lane). Frag row stride 36 dwords
//    -> only 2-way bank aliasing (free, m136).
//  - Single per-wave h scratch reused for h1 and h2 (WAR-safe: per-wave
//    buffer, reads precede writes in program order, LDS in-order per wave).
//    LDS ~37 KB -> 4 blocks/CU.
// MFMA layouts (16x16x32 bf16, HW-verified m89/m91/m120, round-8 end-to-end):
//   A-frag: lane holds A[m=lane&15][k=8*quad+j]; B-frag: B[k=8*quad+j][n=lane&15]
//   C/D: reg r = C[row=4*quad+r][col=lane&15]
// L3 computed swapped (D = W3^T * relu(h2)): quad-0 lanes hold all 4 output
// channels of their sample -> shuffle-free epilogue.
// ---------------------------------------------------------------------------
__global__ __launch_bounds__(256)
void fused_mfma_kernel(const float* __restrict__ rays_o, const float* __restrict__ rays_d,
                       const float* __restrict__ nearv, const float* __restrict__ farv,
                       const float* __restrict__ jitter, const float* __restrict__ density,
                       const float* __restrict__ W1, const float* __restrict__ b1,
                       const float* __restrict__ W2, const float* __restrict__ b2,
                       const float* __restrict__ Wsig, const float* __restrict__ bsig,
                       const float* __restrict__ Wrgb, const float* __restrict__ brgb,
                       float* __restrict__ out, int N)
{
    __shared__ __align__(16) short sW2t[H * 72];       // bf16 W2 transposed [n][k], 9.2 KB
    __shared__ __align__(16) short hX[4][16 * 72];     // per-wave h1/h2 scratch, 9.2 KB
    __shared__ unsigned short s_list[SPB];             // 2 KB
    __shared__ float s_alpha[SPB];                     // 4 KB
    __shared__ float s_r[SPB], s_g[SPB], s_b[SPB];     // 12 KB
    __shared__ int s_wcnt[4];
    __shared__ int s_wbase[4];

    const int tid  = threadIdx.x;
    const int lane = tid & 63;
    const int wv   = tid >> 6;
    const int blk  = blockIdx.x;
    const int mrow = lane & 15;      // 16-dim index (row for A/C, col for B)
    const int quad = lane >> 4;      // k-quad

    // ---- stage W2 bf16 TRANSPOSED into LDS (coalesced global reads) ----
    for (int e = tid; e < H * H; e += T) {
        const int k = e >> 6, n = e & 63;
        sW2t[n * 72 + k] = f2bf(W2[e]);
    }

    // ================= Phase A: mask + block compaction (4 samples/thread) ==
    const int lbase = tid * 4;            // local sample ids lbase..lbase+3
    const int gra   = blk * RPB + (lbase >> 7);
    unsigned int mybits = 0u;
    if (gra < N) {
        const float ox = rays_o[gra * 3 + 0], oy = rays_o[gra * 3 + 1], oz = rays_o[gra * 3 + 2];
        const float dx = rays_d[gra * 3 + 0], dy = rays_d[gra * 3 + 1], dz = rays_d[gra * 3 + 2];
        const float nr = nearv[gra];
        const float step = __fdiv_rn(__fsub_rn(farv[gra], nr), 128.0f);
        const int s0 = lbase & (S - 1);
        #pragma unroll
        for (int j = 0; j < 4; ++j) {
            const bool m = sample_mask(ox, oy, oz, dx, dy, dz, nr, step, s0 + j, density);
            if (m) {
                mybits |= (1u << j);
            } else {
                s_alpha[lbase + j] = 0.0f;
                s_r[lbase + j] = 0.0f;
                s_g[lbase + j] = 0.0f;
                s_b[lbase + j] = 0.0f;
            }
        }
    } else {
        #pragma unroll
        for (int j = 0; j < 4; ++j) {
            s_alpha[lbase + j] = 0.0f;
            s_r[lbase + j] = 0.0f;
            s_g[lbase + j] = 0.0f;
            s_b[lbase + j] = 0.0f;
        }
    }
    const int mycnt = __popc(mybits);
    int inc = mycnt;
    #pragma unroll
    for (int off = 1; off < 64; off <<= 1) {
        const int u = __shfl_up(inc, off, 64);
        if (lane >= off) inc += u;
    }
    if (lane == 63) s_wcnt[wv] = inc;
    __syncthreads();                       // also covers sW2t staging
    if (tid == 0) {
        int t0 = 0;
        #pragma unroll
        for (int i = 0; i < 4; ++i) { s_wbase[i] = t0; t0 += s_wcnt[i]; }
    }
    __syncthreads();
    int pos = s_wbase[wv] + (inc - mycnt);
    #pragma unroll
    for (int j = 0; j < 4; ++j) {
        if ((mybits >> j) & 1u) s_list[pos++] = (unsigned short)(lbase + j);
    }
    __syncthreads();
    const int K = s_wbase[3] + s_wcnt[3];

    // ================= Weight fragments (once per block) ====================
    // W2 B-frags: one ds_read_b128 each from the transposed image.
    bf16x8 w2f[4][2];
    #pragma unroll
    for (int nt = 0; nt < 4; ++nt) {
        #pragma unroll
        for (int ks = 0; ks < 2; ++ks) {
            w2f[nt][ks] = *(const bf16x8*)&sW2t[(mrow + 16 * nt) * 72 + 32 * ks + 8 * quad];
        }
    }
    // W1 B-frags: rows k=0..2 = input dims (bias added fp32 in epilogue)
    bf16x8 w1f[4];
    #pragma unroll
    for (int nt = 0; nt < 4; ++nt) {
        bf16x8 f = {0, 0, 0, 0, 0, 0, 0, 0};
        if (quad == 0) {
            const int n = mrow + 16 * nt;
            f[0] = f2bf(W1[n]);
            f[1] = f2bf(W1[64 + n]);
            f[2] = f2bf(W1[128 + n]);
        }
        w1f[nt] = f;
    }
    // L3 A-frags: A[m=channel][k]; ch0=Wsig, ch1..3=Wrgb
    bf16x8 a3f[2];
    #pragma unroll
    for (int ks = 0; ks < 2; ++ks) {
        bf16x8 f = {0, 0, 0, 0, 0, 0, 0, 0};
        if (mrow < 4) {
            #pragma unroll
            for (int j = 0; j < 8; ++j) {
                const int k = 32 * ks + 8 * quad + j;
                const float v = (mrow == 0) ? Wsig[k] : Wrgb[k * 3 + (mrow - 1)];
                f[j] = f2bf(v);
            }
        }
        a3f[ks] = f;
    }
    float b1v[4], b2v[4];
    #pragma unroll
    for (int nt = 0; nt < 4; ++nt) {
        b1v[nt] = b1[mrow + 16 * nt];
        b2v[nt] = b2[mrow + 16 * nt];
    }
    const float bsg = bsig[0];
    const float br0 = brgb[0], br1 = brgb[1], br2 = brgb[2];

    // ================= Phase B: MFMA MLP over 16-sample tasks ===============
    const f32x4 z4 = {0.f, 0.f, 0.f, 0.f};
    const int ntask = (K + 15) >> 4;
    short* const hb = &hX[wv][0];

    for (int t = wv; t < ntask; t += 4) {
        const int slot = (t << 4) + mrow;
        const bool valid = slot < K;
        const int id = s_list[valid ? slot : 0];
        const int r = blk * RPB + (id >> 7);
        const int s = id & (S - 1);
        const float nr = nearv[r];
        const float step = __fdiv_rn(__fsub_rn(farv[r], nr), 128.0f);
        const float zs = __fadd_rn(nr, __fmul_rn((float)s, step));
        const float zj = zs + jitter[blk * SPB + id] * step;
        const float qx = rays_o[r * 3 + 0] + zj * rays_d[r * 3 + 0];
        const float qy = rays_o[r * 3 + 1] + zj * rays_d[r * 3 + 1];
        const float qz = rays_o[r * 3 + 2] + zj * rays_d[r * 3 + 2];

        // ---- L1: A = pts (k=0..2 on quad 0) ----
        bf16x8 ah = {0, 0, 0, 0, 0, 0, 0, 0};
        if (quad == 0) { ah[0] = f2bf(qx); ah[1] = f2bf(qy); ah[2] = f2bf(qz); }
        #pragma unroll
        for (int nt = 0; nt < 4; ++nt) {
            const f32x4 c1 = MFMA16(ah, w1f[nt], z4);
            #pragma unroll
            for (int rg = 0; rg < 4; ++rg) {
                const float v = fmaxf(c1[rg] + b1v[nt], 0.0f);
                hb[(4 * quad + rg) * 72 + mrow + 16 * nt] = f2bf(v);
            }
        }

        // ---- L2: h2 = relu(h1) @ W2 (reads h1 from hb, then overwrites) ----
        bf16x8 a2_0 = *(const bf16x8*)&hb[mrow * 72 + 8 * quad];
        bf16x8 a2_1 = *(const bf16x8*)&hb[mrow * 72 + 32 + 8 * quad];
        #pragma unroll
        for (int nt = 0; nt < 4; ++nt) {
            const f32x4 c2 = MFMA16(a2_1, w2f[nt][1], MFMA16(a2_0, w2f[nt][0], z4));
            #pragma unroll
            for (int rg = 0; rg < 4; ++rg) {
                const float v = fmaxf(c2[rg] + b2v[nt], 0.0f);
                hb[(4 * quad + rg) * 72 + mrow + 16 * nt] = f2bf(v);
            }
        }

        // ---- L3 (swapped): D = W3^T @ relu(h2); C cols=samples, rows=channels
        bf16x8 b3_0 = *(const bf16x8*)&hb[mrow * 72 + 8 * quad];
        bf16x8 b3_1 = *(const bf16x8*)&hb[mrow * 72 + 32 + 8 * quad];
        const f32x4 c3 = MFMA16(a3f[1], b3_1, MFMA16(a3f[0], b3_0, z4));

        if (quad == 0 && valid) {
            const float sg = c3[0] + bsg;
            const float tau = fmaxf(sg, 0.0f) * step;
            s_alpha[id] = 1.0f - expf(-tau);
            s_r[id] = 1.0f / (1.0f + expf(-(c3[1] + br0)));
            s_g[id] = 1.0f / (1.0f + expf(-(c3[2] + br1)));
            s_b[id] = 1.0f / (1.0f + expf(-(c3[3] + br2)));
        }
    }
    __syncthreads();

    // ================= Phase C: composite (2 rays per wave) =================
    #pragma unroll
    for (int ri = wv; ri < RPB; ri += 4) {
        const int gr = blk * RPB + ri;
        if (gr >= N) break;
        const int b0 = ri * S + 2 * lane;
        const float2 a01 = *reinterpret_cast<const float2*>(&s_alpha[b0]);
        const float a0 = a01.x, a1 = a01.y;
        const float t0 = (1.0f - a0) + 1e-10f;
        const float t1 = (1.0f - a1) + 1e-10f;
        float v = t0 * t1;
        #pragma unroll
        for (int off = 1; off < 64; off <<= 1) {
            const float u = __shfl_up(v, off, 64);
            if (lane >= off) v *= u;
        }
        float excl = __shfl_up(v, 1, 64);
        if (lane == 0) excl = 1.0f;
        const float no_hit = __shfl(v, 63, 64);
        const float w0 = a0 * excl;
        const float w1 = a1 * (excl * t0);
        const float2 r01 = *reinterpret_cast<const float2*>(&s_r[b0]);
        const float2 g01 = *reinterpret_cast<const float2*>(&s_g[b0]);
        const float2 b01 = *reinterpret_cast<const float2*>(&s_b[b0]);
        float cr = w0 * r01.x + w1 * r01.y;
        float cg = w0 * g01.x + w1 * g01.y;
        float cb = w0 * b01.x + w1 * b01.y;
        #pragma unroll
        for (int off = 32; off >= 1; off >>= 1) {
            cr += __shfl_xor(cr, off, 64);
            cg += __shfl_xor(cg, off, 64);
            cb += __shfl_xor(cb, off, 64);
        }
        if (lane == 0) {
            out[gr * 3 + 0] = cr + no_hit;
            out[gr * 3 + 1] = cg + no_hit;
            out[gr * 3 + 2] = cb + no_hit;
        }
    }
}

extern "C" void kernel_launch(void* const* d_in, const int* in_sizes, int n_in,
                              void* d_out, int out_size, void* d_ws, size_t ws_size,
                              hipStream_t stream) {
    const float* rays_o  = (const float*)d_in[0];
    const float* rays_d  = (const float*)d_in[1];
    const float* nearv   = (const float*)d_in[2];
    const float* farv    = (const float*)d_in[3];
    const float* jitter  = (const float*)d_in[4];
    const float* density = (const float*)d_in[5];
    const float* W1      = (const float*)d_in[6];
    const float* b1      = (const float*)d_in[7];
    const float* W2      = (const float*)d_in[8];
    const float* b2      = (const float*)d_in[9];
    const float* Wsig    = (const float*)d_in[10];
    const float* bsig    = (const float*)d_in[11];
    const float* Wrgb    = (const float*)d_in[12];
    const float* brgb    = (const float*)d_in[13];
    float* out = (float*)d_out;

    const int N = in_sizes[2];

    fused_mfma_kernel<<<dim3((N + RPB - 1) / RPB), dim3(T), 0, stream>>>(
        rays_o, rays_d, nearv, farv, jitter, density,
        W1, b1, W2, b2, Wsig, bsig, Wrgb, brgb, out, N);
}